// Round 14
// baseline (143.408 us; speedup 1.0000x reference)
//
#include <hip/hip_runtime.h>
#include <stdint.h>

#define N_ROWS 8192
#define C_IN   4096
#define C_OUT  4096
#define NCHUNK (C_IN / 64)     // 64 chunks of BK=64 (one 32x32x64 MFMA K-slab)
#define MT4    65536           // bytes per 32-row slab in fp4 frag file

typedef int   v4i  __attribute__((ext_vector_type(4)));
typedef float v16f __attribute__((ext_vector_type(16)));

// ======================================================================
// pack v2 (no LDS, pure bit ops): thread (row, kb) reads 64 consecutive
// floats (256 B; a wave sweeps one full 16 KB row contiguously) and
// writes the two 16-B frag pieces directly:
//   piece_hi at frag[mt][kb][(hi*32+rl)*16], byte j <- floats hi*32+2j,2j+1
//   nibble = 0x2 | signbit<<3  (+1 -> 0x2, -1 -> 0xA; +0.0 -> +1,
//   measure-zero deviation, error 2*ab ~ 0.025 << 0.092 threshold)
// dword d = 0x22222222 | sum (u_i & 0x80000000) >> (28-4i), i = float 8d+i.
// Scattered 16B writes at 1024-B stride: each 64-B line is completed by
// the 4 consecutive rows inside the same block -> L2 write-merge.
// ======================================================================
__global__ void pack_all_kernel(const float* __restrict__ x,
                                const float* __restrict__ w,
                                uint8_t* __restrict__ xf,
                                uint8_t* __restrict__ wf,
                                float* __restrict__ partials) {
    __shared__ float sacc[4];

    const int b = blockIdx.x;
    const float* src; uint8_t* dst; int unit0;
    if (b < 2048) { src = x; dst = xf; unit0 = b * 256; }          // x: 8192 rows
    else          { src = w; dst = wf; unit0 = (b - 2048) * 256; } // w: 4096 rows

    const int t    = threadIdx.x;
    const int unit = unit0 + t;
    const int row  = unit >> 6;     // global row
    const int kb   = unit & 63;
    const int mt   = row >> 5, rl = row & 31;

    const float4* p = (const float4*)(src + (size_t)row * C_IN + kb * 64);
    uint32_t pw[8];
    float s = 0.f;
#pragma unroll
    for (int d = 0; d < 8; ++d) {
        float4 a = p[2 * d], c = p[2 * d + 1];
        uint32_t u0 = __float_as_uint(a.x), u1 = __float_as_uint(a.y);
        uint32_t u2 = __float_as_uint(a.z), u3 = __float_as_uint(a.w);
        uint32_t u4 = __float_as_uint(c.x), u5 = __float_as_uint(c.y);
        uint32_t u6 = __float_as_uint(c.z), u7 = __float_as_uint(c.w);
        pw[d] = 0x22222222u
              | ((u0 & 0x80000000u) >> 28) | ((u1 & 0x80000000u) >> 24)
              | ((u2 & 0x80000000u) >> 20) | ((u3 & 0x80000000u) >> 16)
              | ((u4 & 0x80000000u) >> 12) | ((u5 & 0x80000000u) >> 8)
              | ((u6 & 0x80000000u) >> 4)  |  (u7 & 0x80000000u);
        s += fabsf(a.x) + fabsf(a.y) + fabsf(a.z) + fabsf(a.w)
           + fabsf(c.x) + fabsf(c.y) + fabsf(c.z) + fabsf(c.w);
    }
    uint8_t* out0 = dst + (size_t)mt * MT4 + (size_t)kb * 1024 + rl * 16;
    uint4 lo; lo.x = pw[0]; lo.y = pw[1]; lo.z = pw[2]; lo.w = pw[3];
    uint4 hi; hi.x = pw[4]; hi.y = pw[5]; hi.z = pw[6]; hi.w = pw[7];
    *(uint4*)(out0)       = lo;   // hi-half 0: k 0..31
    *(uint4*)(out0 + 512) = hi;   // hi-half 1: k 32..63  ((32+rl)*16)

    // deterministic block reduction of sum|v|
    for (int off = 32; off > 0; off >>= 1) s += __shfl_down(s, off, 64);
    const int lane = t & 63, wv = t >> 6;
    if (lane == 0) sacc[wv] = s;
    __syncthreads();
    if (t == 0) {
        float acc = 0.f;
        for (int i = 0; i < 4; ++i) acc += sacc[i];
        partials[b] = acc;
    }
}

// ---- deterministic final reduction -> alpha*betta ----
__global__ void finalize_kernel(const float* __restrict__ part_x, int nx,
                                const float* __restrict__ part_w, int nw,
                                float* __restrict__ out_ab) {
    __shared__ float s[256];
    float ax = 0.f;
    for (int i = threadIdx.x; i < nx; i += 256) ax += part_x[i];
    s[threadIdx.x] = ax; __syncthreads();
    for (int st = 128; st > 0; st >>= 1) {
        if (threadIdx.x < st) s[threadIdx.x] += s[threadIdx.x + st];
        __syncthreads();
    }
    float sumx = s[0];
    __syncthreads();
    float aw = 0.f;
    for (int i = threadIdx.x; i < nw; i += 256) aw += part_w[i];
    s[threadIdx.x] = aw; __syncthreads();
    for (int st = 128; st > 0; st >>= 1) {
        if (threadIdx.x < st) s[threadIdx.x] += s[threadIdx.x + st];
        __syncthreads();
    }
    if (threadIdx.x == 0) {
        float sumw = s[0];
        float alpha = sumw / (float)((long long)C_OUT * C_IN);
        float betta = sumx / (float)((long long)N_ROWS * C_IN);
        out_ab[0] = alpha * betta;
    }
}

// ======================================================================
// MX-FP4 MFMA GEMM — round-13 kernel, UNCHANGED (measured stable 79 us,
// 3.48 PF = documented fp4 plateau). 256x256 tile, 8 waves (2x4),
// per-wave 128x64; 4-deep LDS buffers; stage c+2; counted vmcnt(2);
// one barrier per chunk; conflict-free lane*16 reads.
// ======================================================================
#define MF(a, b, c) \
    __builtin_amdgcn_mfma_scale_f32_32x32x64_f8f6f4( \
        __builtin_shufflevector((a), (a), 0, 1, 2, 3, -1, -1, -1, -1), \
        __builtin_shufflevector((b), (b), 0, 1, 2, 3, -1, -1, -1, -1), \
        (c), 4, 4, 0, 127, 0, 127)

__launch_bounds__(512)
__global__ void xnor_gemm_fp4(const uint8_t* __restrict__ Afrag,
                              const uint8_t* __restrict__ Bfrag,
                              const float* __restrict__ bias,
                              const float* __restrict__ ab_ptr,
                              float* __restrict__ out) {
    __shared__ __align__(16) uint8_t lds[4][2][8192];  // 64 KB

    const int t    = threadIdx.x;
    const int lane = t & 63;
    const int hi   = lane >> 5;
    const int r    = lane & 31;
    const int wid  = t >> 6;
    const int wr   = wid >> 2;   // 0..1 (M waves)
    const int wc   = wid & 3;    // 0..3 (N waves)

    // XCD-aware swizzle over 512 blocks (divisible by 8)
    const int id  = blockIdx.x;
    const int swz = (id & 7) * 64 + (id >> 3);
    const int brow = (swz >> 4) * 256;
    const int bcol = (swz & 15) * 256;

    const uint8_t* Abase = Afrag + (size_t)(brow >> 5) * MT4;
    const uint8_t* Bbase = Bfrag + (size_t)(bcol >> 5) * MT4;
    const size_t soff = (size_t)(t >> 6) * MT4 + (size_t)(t & 63) * 16;

#define STG(BUF, c)                                                                     \
    do {                                                                                \
        size_t ka = (size_t)(c) * 1024;                                                 \
        __builtin_amdgcn_global_load_lds(                                               \
            (const __attribute__((address_space(1))) void*)(Abase + soff + ka),         \
            (__attribute__((address_space(3))) void*)(&lds[BUF][0][t * 16]), 16, 0, 0); \
        __builtin_amdgcn_global_load_lds(                                               \
            (const __attribute__((address_space(1))) void*)(Bbase + soff + ka),         \
            (__attribute__((address_space(3))) void*)(&lds[BUF][1][t * 16]), 16, 0, 0); \
    } while (0)

    v16f acc[4][2] = {};

    STG(0, 0); STG(1, 1);   // 4 loads in flight (A0,B0,A1,B1)

#pragma unroll 4
    for (int ck = 0; ck < NCHUNK; ++ck) {
        const int buf = ck & 3;
        if (ck < NCHUNK - 2) { asm volatile("s_waitcnt vmcnt(2)" ::: "memory"); }
        else                 { asm volatile("s_waitcnt vmcnt(0)" ::: "memory"); }
        __builtin_amdgcn_s_barrier();

        v4i a4[4], b4[2];
#pragma unroll
        for (int m = 0; m < 4; ++m)
            a4[m] = *(const v4i*)(&lds[buf][0][((wr * 4 + m) * 64 + lane) * 16]);
#pragma unroll
        for (int n = 0; n < 2; ++n)
            b4[n] = *(const v4i*)(&lds[buf][1][((wc * 2 + n) * 64 + lane) * 16]);

        if (ck + 2 < NCHUNK) STG((ck + 2) & 3, ck + 2);

#pragma unroll
        for (int m = 0; m < 4; ++m)
#pragma unroll
            for (int n = 0; n < 2; ++n)
                acc[m][n] = MF(a4[m], b4[n], acc[m][n]);
    }

    const float ab = ab_ptr[0];
#pragma unroll
    for (int m = 0; m < 4; ++m) {
#pragma unroll
        for (int n = 0; n < 2; ++n) {
            int col = bcol + wc * 64 + n * 32 + r;
            float bv = bias[col];
#pragma unroll
            for (int reg = 0; reg < 16; ++reg) {
                int rowf = (reg & 3) + 8 * (reg >> 2) + 4 * hi;   // C/D layout (shape-determined)
                int grow = brow + wr * 128 + m * 32 + rowf;
                out[(size_t)grow * C_OUT + col] = acc[m][n][reg] * ab + bv;
            }
        }
    }
#undef STG
}

// ======================================================================
extern "C" void kernel_launch(void* const* d_in, const int* in_sizes, int n_in,
                              void* d_out, int out_size, void* d_ws, size_t ws_size,
                              hipStream_t stream) {
    const float* x    = (const float*)d_in[0];
    const float* w    = (const float*)d_in[1];
    const float* bias = (const float*)d_in[2];
    float* out = (float*)d_out;

    char* ws = (char*)d_ws;
    float* red      = (float*)ws;      // red[0] = alpha*betta
    float* partials = red + 16;        // 3072 partials (x: 0..2047, w: 2048..3071)
    uint8_t* xs  = (uint8_t*)(ws + 16384);             // 16 MB fp4 frag file (x)
    uint8_t* wsg = xs + (size_t)N_ROWS * C_IN / 2;     // 8 MB fp4 frag file (w)

    pack_all_kernel<<<3072, 256, 0, stream>>>(x, w, xs, wsg, partials);
    finalize_kernel<<<1, 256, 0, stream>>>(partials, 2048, partials + 2048, 1024, red);

    dim3 grid((N_ROWS / 256) * (C_OUT / 256));  // 512
    xnor_gemm_fp4<<<grid, 512, 0, stream>>>(xs, wsg, bias, red, out);
}

// Round 15
// 131.264 us; speedup vs baseline: 1.0925x; 1.0925x over previous
//
#include <hip/hip_runtime.h>
#include <stdint.h>

#define N_ROWS 8192
#define C_IN   4096
#define C_OUT  4096
#define NCHUNK (C_IN / 64)     // 64 chunks of BK=64 (one 32x32x64 MFMA K-slab)
#define MT4    65536           // bytes per 32-row slab in fp4 frag file

typedef int   v4i  __attribute__((ext_vector_type(4)));
typedef float v16f __attribute__((ext_vector_type(16)));

// ======================================================================
// pack v1 (LDS-transpose, proven r6-r13): f32 -> fp4 e2m1 sign
// (+ -> 0x2, - -> 0xA), frag-ordered. Reads: 8 lanes x 16 B per 128-B
// row segment (every line fully consumed per instruction). Nibble build
// via sign-bit trick (verified equivalent in r14's passing run).
// ======================================================================
__global__ void pack_all_kernel(const float* __restrict__ x,
                                const float* __restrict__ w,
                                uint8_t* __restrict__ xf,
                                uint8_t* __restrict__ wf,
                                float* __restrict__ partials) {
    __shared__ __align__(16) uint16_t tile16[4096];   // 8 KB
    __shared__ float sacc[4];

    const int b = blockIdx.x;
    const float* src; uint8_t* dst; int slab;
    if (b < 2048) { src = x; dst = xf; slab = b; }        // x: 256 mt x 8 cg
    else          { src = w; dst = wf; slab = b - 2048; } // w: 128 mt x 8 cg
    const int mt = slab >> 3, cg = slab & 7;

    const int t = threadIdx.x;
    const int r = t >> 3, lc = t & 7;

    const float4* base = (const float4*)(src + (size_t)(mt * 32 + r) * C_IN + cg * 512) + lc;
    float acc = 0.f;
#pragma unroll
    for (int it = 0; it < 16; ++it) {
        float4 v = base[it * 8];
        uint32_t u0 = __float_as_uint(v.x), u1 = __float_as_uint(v.y);
        uint32_t u2 = __float_as_uint(v.z), u3 = __float_as_uint(v.w);
        uint16_t nv = (uint16_t)(0x2222u
                    | ((u0 & 0x80000000u) >> 28) | ((u1 & 0x80000000u) >> 24)
                    | ((u2 & 0x80000000u) >> 20) | ((u3 & 0x80000000u) >> 16));
        acc += fabsf(v.x) + fabsf(v.y) + fabsf(v.z) + fabsf(v.w);
        tile16[it * 256 + t] = nv;
    }
    __syncthreads();
    uint4* gout = (uint4*)(dst + (size_t)mt * MT4 + (size_t)cg * 8192);
    const uint4* lin = (const uint4*)tile16;
#pragma unroll
    for (int p = 0; p < 2; ++p) gout[p * 256 + t] = lin[p * 256 + t];

    for (int off = 32; off > 0; off >>= 1) acc += __shfl_down(acc, off, 64);
    const int lane = t & 63, wv = t >> 6;
    if (lane == 0) sacc[wv] = acc;
    __syncthreads();
    if (t == 0) {
        float s = 0.f;
        for (int i = 0; i < 4; ++i) s += sacc[i];
        partials[b] = s;
    }
}

// ---- deterministic final reduction -> alpha*betta ----
__global__ void finalize_kernel(const float* __restrict__ part_x, int nx,
                                const float* __restrict__ part_w, int nw,
                                float* __restrict__ out_ab) {
    __shared__ float s[256];
    float ax = 0.f;
    for (int i = threadIdx.x; i < nx; i += 256) ax += part_x[i];
    s[threadIdx.x] = ax; __syncthreads();
    for (int st = 128; st > 0; st >>= 1) {
        if (threadIdx.x < st) s[threadIdx.x] += s[threadIdx.x + st];
        __syncthreads();
    }
    float sumx = s[0];
    __syncthreads();
    float aw = 0.f;
    for (int i = threadIdx.x; i < nw; i += 256) aw += part_w[i];
    s[threadIdx.x] = aw; __syncthreads();
    for (int st = 128; st > 0; st >>= 1) {
        if (threadIdx.x < st) s[threadIdx.x] += s[threadIdx.x + st];
        __syncthreads();
    }
    if (threadIdx.x == 0) {
        float sumw = s[0];
        float alpha = sumw / (float)((long long)C_OUT * C_IN);
        float betta = sumx / (float)((long long)N_ROWS * C_IN);
        out_ab[0] = alpha * betta;
    }
}

// ======================================================================
// MX-FP4 MFMA GEMM — round-13 kernel, UNCHANGED (stable 78-79 us across
// 8 structural variants; 3.48 PF = documented fp4 plateau, m160: 3445 TF).
// 256x256 tile, 8 waves (2x4), per-wave 128x64; 4-deep LDS buffers;
// stage c+2; counted vmcnt(2); one barrier per chunk; conflict-free
// lane*16 LDS reads.
// ======================================================================
#define MF(a, b, c) \
    __builtin_amdgcn_mfma_scale_f32_32x32x64_f8f6f4( \
        __builtin_shufflevector((a), (a), 0, 1, 2, 3, -1, -1, -1, -1), \
        __builtin_shufflevector((b), (b), 0, 1, 2, 3, -1, -1, -1, -1), \
        (c), 4, 4, 0, 127, 0, 127)

__launch_bounds__(512)
__global__ void xnor_gemm_fp4(const uint8_t* __restrict__ Afrag,
                              const uint8_t* __restrict__ Bfrag,
                              const float* __restrict__ bias,
                              const float* __restrict__ ab_ptr,
                              float* __restrict__ out) {
    __shared__ __align__(16) uint8_t lds[4][2][8192];  // 64 KB

    const int t    = threadIdx.x;
    const int lane = t & 63;
    const int hi   = lane >> 5;
    const int r    = lane & 31;
    const int wid  = t >> 6;
    const int wr   = wid >> 2;   // 0..1 (M waves)
    const int wc   = wid & 3;    // 0..3 (N waves)

    // XCD-aware swizzle over 512 blocks (divisible by 8)
    const int id  = blockIdx.x;
    const int swz = (id & 7) * 64 + (id >> 3);
    const int brow = (swz >> 4) * 256;
    const int bcol = (swz & 15) * 256;

    const uint8_t* Abase = Afrag + (size_t)(brow >> 5) * MT4;
    const uint8_t* Bbase = Bfrag + (size_t)(bcol >> 5) * MT4;
    const size_t soff = (size_t)(t >> 6) * MT4 + (size_t)(t & 63) * 16;

#define STG(BUF, c)                                                                     \
    do {                                                                                \
        size_t ka = (size_t)(c) * 1024;                                                 \
        __builtin_amdgcn_global_load_lds(                                               \
            (const __attribute__((address_space(1))) void*)(Abase + soff + ka),         \
            (__attribute__((address_space(3))) void*)(&lds[BUF][0][t * 16]), 16, 0, 0); \
        __builtin_amdgcn_global_load_lds(                                               \
            (const __attribute__((address_space(1))) void*)(Bbase + soff + ka),         \
            (__attribute__((address_space(3))) void*)(&lds[BUF][1][t * 16]), 16, 0, 0); \
    } while (0)

    v16f acc[4][2] = {};

    STG(0, 0); STG(1, 1);   // 4 loads in flight (A0,B0,A1,B1)

#pragma unroll 4
    for (int ck = 0; ck < NCHUNK; ++ck) {
        const int buf = ck & 3;
        if (ck < NCHUNK - 2) { asm volatile("s_waitcnt vmcnt(2)" ::: "memory"); }
        else                 { asm volatile("s_waitcnt vmcnt(0)" ::: "memory"); }
        __builtin_amdgcn_s_barrier();

        v4i a4[4], b4[2];
#pragma unroll
        for (int m = 0; m < 4; ++m)
            a4[m] = *(const v4i*)(&lds[buf][0][((wr * 4 + m) * 64 + lane) * 16]);
#pragma unroll
        for (int n = 0; n < 2; ++n)
            b4[n] = *(const v4i*)(&lds[buf][1][((wc * 2 + n) * 64 + lane) * 16]);

        if (ck + 2 < NCHUNK) STG((ck + 2) & 3, ck + 2);

#pragma unroll
        for (int m = 0; m < 4; ++m)
#pragma unroll
            for (int n = 0; n < 2; ++n)
                acc[m][n] = MF(a4[m], b4[n], acc[m][n]);
    }

    const float ab = ab_ptr[0];
#pragma unroll
    for (int m = 0; m < 4; ++m) {
#pragma unroll
        for (int n = 0; n < 2; ++n) {
            int col = bcol + wc * 64 + n * 32 + r;
            float bv = bias[col];
#pragma unroll
            for (int reg = 0; reg < 16; ++reg) {
                int rowf = (reg & 3) + 8 * (reg >> 2) + 4 * hi;   // C/D layout (shape-determined)
                int grow = brow + wr * 128 + m * 32 + rowf;
                out[(size_t)grow * C_OUT + col] = acc[m][n][reg] * ab + bv;
            }
        }
    }
#undef STG
}

// ======================================================================
extern "C" void kernel_launch(void* const* d_in, const int* in_sizes, int n_in,
                              void* d_out, int out_size, void* d_ws, size_t ws_size,
                              hipStream_t stream) {
    const float* x    = (const float*)d_in[0];
    const float* w    = (const float*)d_in[1];
    const float* bias = (const float*)d_in[2];
    float* out = (float*)d_out;

    char* ws = (char*)d_ws;
    float* red      = (float*)ws;      // red[0] = alpha*betta
    float* partials = red + 16;        // 3072 partials (x: 0..2047, w: 2048..3071)
    uint8_t* xs  = (uint8_t*)(ws + 16384);             // 16 MB fp4 frag file (x)
    uint8_t* wsg = xs + (size_t)N_ROWS * C_IN / 2;     // 8 MB fp4 frag file (w)

    pack_all_kernel<<<3072, 256, 0, stream>>>(x, w, xs, wsg, partials);
    finalize_kernel<<<1, 256, 0, stream>>>(partials, 2048, partials + 2048, 1024, red);

    dim3 grid((N_ROWS / 256) * (C_OUT / 256));  // 512
    xnor_gemm_fp4<<<grid, 512, 0, stream>>>(xs, wsg, bias, red, out);
}